// Round 1
// baseline (1160.811 us; speedup 1.0000x reference)
//
#include <hip/hip_runtime.h>

#define IN_DIM   512
#define OUT_DIM  256
#define N_MID    1280
#define N_NODES  1792
#define BATCH    16384
#define ROWS     16     // batch rows per workgroup
#define NT       256    // threads per workgroup
#define XPAD     520    // LDS row stride for x tile (bank-conflict-free broadcast)

// thread t: rg = t&3 -> rows {rg, rg+4, rg+8, rg+12}
//           cg = t>>2 in [0,64) -> columns [cg*20, cg*20+20)
// acc[4][20] fp32 per thread (80 VGPR). Column i owned by cg = i/20, k = i%20.

__global__ void effw_kernel(const float* __restrict__ w, const int* __restrict__ c,
                            float* __restrict__ ew, int n) {
    int i = blockIdx.x * NT + threadIdx.x;
    if (i < n) ew[i] = w[i] * (float)c[i];
}

template <bool FOLD>
__device__ __forceinline__ float4 load_w4(const float* __restrict__ wsrc,
                                          const int* __restrict__ conn, size_t off) {
    float4 w4 = *(const float4*)(wsrc + off);
    if (FOLD) {
        int4 c4 = *(const int4*)(conn + off);
        w4.x *= (float)c4.x; w4.y *= (float)c4.y;
        w4.z *= (float)c4.z; w4.w *= (float)c4.w;
    }
    return w4;
}

template <bool FOLD>
__global__ __launch_bounds__(NT, 4)
void net_kernel(const float* __restrict__ x,
                const float* __restrict__ wsrc,   // eff_w (FOLD=false) or raw weight (FOLD=true)
                const int* __restrict__ conn,     // used only when FOLD
                const float* __restrict__ bias,
                const int* __restrict__ exist,
                float* __restrict__ out) {
    __shared__ float xs[ROWS * XPAD];   // 33,280 B; overlaid with bias/exist after phase 1
    __shared__ float res_s[2][ROWS];
    float* bias_s  = xs;                // [0, 1280)
    float* exist_s = xs + N_MID;        // [1280, 2560)

    const int t  = threadIdx.x;
    const int rg = t & 3;
    const int cg = t >> 2;
    const int r0 = blockIdx.x * ROWS;
    const int c0 = cg * 20;

    // ---- stage x tile (rows contiguous in global, so flat float4 copy) ----
    {
        const float4* xg = (const float4*)(x + (size_t)r0 * IN_DIM);
        for (int idx = t; idx < ROWS * IN_DIM / 4; idx += NT) {
            int r  = idx >> 7;    // / (512/4)
            int jj = idx & 127;
            *(float4*)&xs[r * XPAD + jj * 4] = xg[idx];
        }
    }
    __syncthreads();

    float acc[4][20];
#pragma unroll
    for (int a = 0; a < 4; ++a)
#pragma unroll
        for (int k = 0; k < 20; ++k) acc[a][k] = 0.f;

    // ---- phase 1: input GEMM  acc[r][m] += x[r][j] * W[j][m] ----
    for (int j = 0; j < IN_DIM; ++j) {
        const size_t woff = (size_t)j * N_MID + c0;
        const float xv0 = xs[(rg     ) * XPAD + j];
        const float xv1 = xs[(rg +  4) * XPAD + j];
        const float xv2 = xs[(rg +  8) * XPAD + j];
        const float xv3 = xs[(rg + 12) * XPAD + j];
#pragma unroll
        for (int q = 0; q < 5; ++q) {
            float4 w4 = load_w4<FOLD>(wsrc, conn, woff + q * 4);
            const float wq[4] = {w4.x, w4.y, w4.z, w4.w};
#pragma unroll
            for (int u = 0; u < 4; ++u) {
                const int k = q * 4 + u;
                acc[0][k] = fmaf(xv0, wq[u], acc[0][k]);
                acc[1][k] = fmaf(xv1, wq[u], acc[1][k]);
                acc[2][k] = fmaf(xv2, wq[u], acc[2][k]);
                acc[3][k] = fmaf(xv3, wq[u], acc[3][k]);
            }
        }
    }
    __syncthreads();

    // ---- overlay bias / existence into LDS (x tile no longer needed) ----
    for (int idx = t; idx < N_MID; idx += NT) {
        bias_s[idx]  = bias[idx];
        exist_s[idx] = (float)exist[idx];
    }
    __syncthreads();

    // ---- phase 2: sequential nodes, rank-1 updates on register-resident acc ----
    int p = 0;
    for (int bb = 0; bb < 64; ++bb) {
#pragma unroll
        for (int kk = 0; kk < 20; ++kk) {
            const int i = bb * 20 + kk;
            const float e = exist_s[i];          // block-uniform
            if (e != 0.f) {
                if (cg == bb) {                   // 4 owner threads compute 16 res values
                    const float bv = bias_s[i];
#pragma unroll
                    for (int a = 0; a < 4; ++a) {
                        const float v = acc[a][kk];               // static index
                        const float s = __fdividef(1.f, 1.f + __expf(-v));
                        const float res = (s + bv) * e;
                        res_s[p][rg + 4 * a] = res;
                        if (i >= N_MID - OUT_DIM)
                            out[(size_t)(r0 + rg + 4 * a) * OUT_DIM + (i - (N_MID - OUT_DIM))] = res;
                    }
                }
                __syncthreads();
                const float rv0 = res_s[p][rg];
                const float rv1 = res_s[p][rg + 4];
                const float rv2 = res_s[p][rg + 8];
                const float rv3 = res_s[p][rg + 12];
                const size_t woff = (size_t)(IN_DIM + i) * N_MID + c0;
                if (cg > bb) {                    // full 20-column update
#pragma unroll
                    for (int q = 0; q < 5; ++q) {
                        float4 w4 = load_w4<FOLD>(wsrc, conn, woff + q * 4);
                        const float wq[4] = {w4.x, w4.y, w4.z, w4.w};
#pragma unroll
                        for (int u = 0; u < 4; ++u) {
                            const int k = q * 4 + u;
                            acc[0][k] = fmaf(rv0, wq[u], acc[0][k]);
                            acc[1][k] = fmaf(rv1, wq[u], acc[1][k]);
                            acc[2][k] = fmaf(rv2, wq[u], acc[2][k]);
                            acc[3][k] = fmaf(rv3, wq[u], acc[3][k]);
                        }
                    }
                } else if (cg == bb) {            // in-block triangular tail (static k > kk)
#pragma unroll
                    for (int k = kk + 1; k < 20; ++k) {
                        float w = wsrc[woff + k];
                        if (FOLD) w *= (float)conn[woff + k];
                        acc[0][k] = fmaf(rv0, w, acc[0][k]);
                        acc[1][k] = fmaf(rv1, w, acc[1][k]);
                        acc[2][k] = fmaf(rv2, w, acc[2][k]);
                        acc[3][k] = fmaf(rv3, w, acc[3][k]);
                    }
                }
                p ^= 1;                           // block-uniform parity of existing steps
            }
        }
    }
}

extern "C" void kernel_launch(void* const* d_in, const int* in_sizes, int n_in,
                              void* d_out, int out_size, void* d_ws, size_t ws_size,
                              hipStream_t stream) {
    const float* x      = (const float*)d_in[0];
    const float* weight = (const float*)d_in[1];
    const float* bias   = (const float*)d_in[2];
    const int*   conn   = (const int*)d_in[3];
    const int*   exist  = (const int*)d_in[4];
    float*       out    = (float*)d_out;

    const size_t ew_elems = (size_t)N_NODES * N_MID;       // 2,293,760
    const size_t ew_bytes = ew_elems * sizeof(float);      // ~9.2 MB

    if (ws_size >= ew_bytes) {
        float* ew = (float*)d_ws;
        effw_kernel<<<(int)(ew_elems / NT), NT, 0, stream>>>(weight, conn, ew, (int)ew_elems);
        net_kernel<false><<<BATCH / ROWS, NT, 0, stream>>>(x, ew, nullptr, bias, exist, out);
    } else {
        net_kernel<true><<<BATCH / ROWS, NT, 0, stream>>>(x, weight, conn, bias, exist, out);
    }
}